// Round 9
// baseline (555.765 us; speedup 1.0000x reference)
//
#include <hip/hip_runtime.h>
#include <hip/hip_cooperative_groups.h>

namespace cg = cooperative_groups;

// Problem constants (from reference)
constexpr int   NB         = 128;          // bins per axis
constexpr int   NCELL      = NB * NB;      // 16384 cells
constexpr int   NFL        = 2 * NCELL;    // [Dx | Dy] floats = 32768
constexpr int   NF4        = NFL / 4;      // 8192 float4 columns
constexpr float S          = 7.8125f;      // 1000/128, exact in fp32
constexpr int   NUM_NETS   = 100000;
constexpr int   NUM_NODES  = 200000;
constexpr int   NUM_MOVABLE= 180000;
constexpr int   NUM_PINS   = 400000;
constexpr float UNIT_H_CAP = 1.5f;
constexpr float UNIT_V_CAP = 1.4f;

#define TPB  1024      // 16 waves/CU
#define NDB  256       // cooperative grid: exactly 1 block per CU

__device__ __forceinline__ float edgef(int t) { return (float)t * S; }

__device__ __forceinline__ int bin_of(float v) {
    int t = (int)floorf(v / S);
    while (edgef(t + 1) <= v) ++t;
    while (edgef(t)     >  v) --t;
    return t;
}

__device__ __forceinline__ float phi(int t, float lo, float hi) {
    return fminf(fmaxf(edgef(t), lo), hi);
}

// ONE cooperative kernel = the whole pipeline. 256 blocks x 1024 thr,
// 128 KB dynamic LDS (1 block/CU co-resident). Phases separated by
// grid.sync(); __threadfence() before each sync for cross-XCD visibility
// (per-XCD L2s are not coherent — G16).
//   P1 net_diff  -> P[b][NFL]       (R6 pin-parallel, linear LDS)
//   P2 reduce    -> R[NFL]          (32 f4-cols/block, 32-way slice split)
//   P3 scan_x    -> Xp[NCELL]f2     (128 blocks, Hillis-Steele, barrier-safe)
//   P4 scan_y    -> util[NCELL]     (128 blocks)
//   P5 node      -> out[NUM_MOVABLE]
// Rationale: rounds 5-8 showed each phase near its own floor; the ~20 us of
// inter-dispatch gaps (5 dispatches x ~4 us) is the largest controllable
// cost left. Fusion trades 4 gaps for 4 grid-syncs.
__global__ __launch_bounds__(TPB) void fused_kernel(
    const float* __restrict__ pos,
    const float* __restrict__ pin_pos,
    const float* __restrict__ nsx,
    const float* __restrict__ nsy,
    const float* __restrict__ net_weights,
    const int*   __restrict__ nps,
    const int*   __restrict__ fnp,
    float* __restrict__ P,      // [B][NFL]
    float* __restrict__ R,      // [NFL]
    float* __restrict__ Xp,     // [NCELL] float2
    float* __restrict__ util,   // [NCELL]
    float* __restrict__ out,    // [NUM_MOVABLE]
    int B) {
    extern __shared__ float Dl[];      // 128 KB, reused per phase
    cg::grid_group grid = cg::this_grid();
    const int tid = threadIdx.x;
    const int bid = blockIdx.x;

    // ---------------- P1: per-block density map + P write ----------------
    if (bid < B) {
        float4* D4 = (float4*)Dl;
        for (int i = tid; i < NF4; i += TPB) D4[i] = make_float4(0, 0, 0, 0);
        __syncthreads();

        const int per = (NUM_NETS + B - 1) / B;
        const int n0  = bid * per;
        const int n1  = min(n0 + per, NUM_NETS);
        const int l   = tid & 3;       // lane within 4-lane group (pin idx)
        const int g   = tid >> 2;      // group id within block
        constexpr int GP = TPB / 4;    // 256 nets per iteration

        for (int n = n0 + g; n < n1; n += GP) {
            int s = nps[n], e = nps[n + 1];
            bool ok = (e > s);
            float xmin, xmax, ymin, ymax;
            if (ok && (e - s == 4)) {
                int pin = fnp[s + l];          // coalesced across the wave
                float xv = pin_pos[pin];
                float yv = pin_pos[pin + NUM_PINS];
                xmin = xv; xmax = xv; ymin = yv; ymax = yv;
            } else {
                xmin = 1e30f; xmax = -1e30f; ymin = 1e30f; ymax = -1e30f;
                if (ok && l == 0) {            // rare/never: serial fallback
                    for (int p = s; p < e; ++p) {
                        int pin = fnp[p];
                        float px = pin_pos[pin];
                        float py = pin_pos[pin + NUM_PINS];
                        xmin = fminf(xmin, px); xmax = fmaxf(xmax, px);
                        ymin = fminf(ymin, py); ymax = fmaxf(ymax, py);
                    }
                }
            }
            xmin = fminf(xmin, __shfl_xor(xmin, 1));
            xmin = fminf(xmin, __shfl_xor(xmin, 2));
            xmax = fmaxf(xmax, __shfl_xor(xmax, 1));
            xmax = fmaxf(xmax, __shfl_xor(xmax, 2));
            ymin = fminf(ymin, __shfl_xor(ymin, 1));
            ymin = fminf(ymin, __shfl_xor(ymin, 2));
            ymax = fmaxf(ymax, __shfl_xor(ymax, 1));
            ymax = fmaxf(ymax, __shfl_xor(ymax, 2));
            if (!ok) continue;

            float w  = net_weights[n];
            float dx = xmax - xmin, dy = ymax - ymin;
            float cx = (dy > 0.f) ? w / dy : 0.f;   // map_x coeff
            float cy = (dx > 0.f) ? w / dx : 0.f;   // map_y coeff
            if (cx == 0.f && cy == 0.f) continue;

            int ax = bin_of(xmin), bx = bin_of(xmax);
            int row; bool has;
            if      (l == 0) { row = ax;     has = true; }
            else if (l == 1) { row = ax + 1; has = true; }
            else if (l == 2) { row = bx;     has = (bx > ax + 1); }
            else             { row = bx + 1; has = (bx > ax); }
            if (!has || row >= NB) continue;
            float fi = phi(row + 1, xmin, xmax) - 2.f * phi(row, xmin, xmax)
                     + phi(row - 1, xmin, xmax);
            if (fi == 0.f) continue;

            int ay = bin_of(ymin), by = bin_of(ymax);
            #pragma unroll
            for (int j = 0; j < 4; ++j) {
                int col; bool hj;
                if      (j == 0) { col = ay;     hj = true; }
                else if (j == 1) { col = ay + 1; hj = true; }
                else if (j == 2) { col = by;     hj = (by > ay + 1); }
                else             { col = by + 1; hj = (by > ay); }
                if (!hj || col >= NB) continue;
                float fj = phi(col + 1, ymin, ymax) - 2.f * phi(col, ymin, ymax)
                         + phi(col - 1, ymin, ymax);
                float t = fi * fj;
                if (t == 0.f) continue;
                int cell = row * NB + col;
                if (cx != 0.f) atomicAdd(&Dl[cell],         cx * t);
                if (cy != 0.f) atomicAdd(&Dl[NCELL + cell], cy * t);
            }
        }
        __syncthreads();

        float4* Pb = (float4*)(P + (size_t)bid * NFL);
        for (int i = tid; i < NF4; i += TPB) Pb[i] = D4[i];
    }
    __threadfence();
    grid.sync();

    // ---------------- P2: reduce P -> R (full sum) ----------------
    {
        const int c  = tid & 31;           // col within block's window
        const int sg = tid >> 5;           // 0..31 slice group
        int col = bid * 32 + c;            // 0..8191 float4 column
        const float4* P4 = (const float4*)P;
        float4 a = make_float4(0.f, 0.f, 0.f, 0.f);
        for (int b = sg; b < B; b += 32) {
            float4 v = P4[(size_t)b * NF4 + col];
            a.x += v.x; a.y += v.y; a.z += v.z; a.w += v.w;
        }
        float4* sc = (float4*)Dl;          // 32x32 float4 = 16 KB scratch
        sc[sg * 32 + c] = a;
        __syncthreads();
        for (int s = 16; s >= 1; s >>= 1) {
            if (sg < s) {
                float4 u = sc[sg * 32 + c];
                float4 v = sc[(sg + s) * 32 + c];
                u.x += v.x; u.y += v.y; u.z += v.z; u.w += v.w;
                sc[sg * 32 + c] = u;
            }
            __syncthreads();
        }
        if (sg == 0) ((float4*)R)[col] = sc[c];
    }
    __threadfence();
    grid.sync();

    // ---------------- P3: x-prefix (blocks 0..127 = column) ----------------
    {
        float2* sm = (float2*)Dl;
        const bool act = (bid < NB) && (tid < NB);
        const int col = bid;
        float2 cur = make_float2(0.f, 0.f);
        if (act) {
            int idx = tid * NB + col;
            cur = make_float2(R[idx], R[NCELL + idx]);
            sm[tid] = cur;
        }
        __syncthreads();
        #pragma unroll
        for (int off = 1; off < NB; off <<= 1) {
            float2 add = make_float2(0.f, 0.f);
            if (act && tid >= off) add = sm[tid - off];
            __syncthreads();
            if (act) {
                cur.x += add.x; cur.y += add.y;
                sm[tid] = cur;
            }
            __syncthreads();
        }
        if (act) ((float2*)Xp)[tid * NB + col] = cur;
    }
    __threadfence();
    grid.sync();

    // ---------------- P4: y-prefix + clip (blocks 0..127 = row) ----------------
    {
        float2* sm = (float2*)Dl;
        const bool act = (bid < NB) && (tid < NB);
        const int row = bid;
        float2 cur = make_float2(0.f, 0.f);
        if (act) {
            cur = ((const float2*)Xp)[row * NB + tid];
            sm[tid] = cur;
        }
        __syncthreads();
        #pragma unroll
        for (int off = 1; off < NB; off <<= 1) {
            float2 add = make_float2(0.f, 0.f);
            if (act && tid >= off) add = sm[tid - off];
            __syncthreads();
            if (act) {
                cur.x += add.x; cur.y += add.y;
                sm[tid] = cur;
            }
            __syncthreads();
        }
        if (act) {
            constexpr float invx = 1.f / (S * S * UNIT_H_CAP);
            constexpr float invy = 1.f / (S * S * UNIT_V_CAP);
            float u = fmaxf(cur.x * invx, cur.y * invy);
            util[row * NB + tid] = fminf(fmaxf(u, 0.5f), 2.0f);
        }
    }
    __threadfence();
    grid.sync();

    // ---------------- P5: per-movable-node area ----------------
    {
        int m = bid * TPB + tid;
        if (m < NUM_MOVABLE) {
            float x  = pos[m];
            float y  = pos[NUM_NODES + m];
            float xh = x + nsx[m];
            float yh = y + nsy[m];
            int ax = max(0,      (int)floorf(x  / S) - 1);
            int bx = min(NB - 1, (int)floorf(xh / S) + 1);
            int ay = max(0,      (int)floorf(y  / S) - 1);
            int by = min(NB - 1, (int)floorf(yh / S) + 1);
            float acc = 0.f;
            for (int i = ax; i <= bx; ++i) {
                float ov = fminf(edgef(i + 1), xh) - fmaxf(edgef(i), x);
                if (ov <= 0.f) continue;
                float inner = 0.f;
                for (int j = ay; j <= by; ++j) {
                    float ovy = fminf(edgef(j + 1), yh) - fmaxf(edgef(j), y);
                    if (ovy > 0.f) inner += ovy * util[i * NB + j];
                }
                acc += ov * inner;
            }
            out[m] = acc;
        }
    }
}

extern "C" void kernel_launch(void* const* d_in, const int* in_sizes, int n_in,
                              void* d_out, int out_size, void* d_ws, size_t ws_size,
                              hipStream_t stream) {
    const float* pos      = (const float*)d_in[0];
    const float* pin_pos  = (const float*)d_in[1];
    const float* nsx      = (const float*)d_in[2];
    const float* nsy      = (const float*)d_in[3];
    const float* nw       = (const float*)d_in[4];
    const int*   npstart  = (const int*)d_in[5];
    const int*   fnp      = (const int*)d_in[6];
    float*       out      = (float*)d_out;

    // ws layout (floats): R[NFL] | Xp[NFL] | util[NCELL] | P[B*NFL]
    float* w    = (float*)d_ws;
    float* R    = w;                           w += NFL;
    float* Xp   = w;                           w += NFL;
    float* util = w;                           w += NCELL;
    float* P    = w;

    size_t fixed = (size_t)(w - (float*)d_ws) * sizeof(float);
    int B = NDB;
    if (ws_size > fixed) {
        size_t fit = (ws_size - fixed) / ((size_t)NFL * sizeof(float));
        if ((size_t)B > fit) B = (int)fit;
    } else {
        B = 1;
    }
    if (B < 1) B = 1;

    (void)hipFuncSetAttribute((const void*)fused_kernel,
                              hipFuncAttributeMaxDynamicSharedMemorySize,
                              NFL * (int)sizeof(float));

    void* args[] = {
        (void*)&pos, (void*)&pin_pos, (void*)&nsx, (void*)&nsy,
        (void*)&nw, (void*)&npstart, (void*)&fnp,
        (void*)&P, (void*)&R, (void*)&Xp, (void*)&util, (void*)&out,
        (void*)&B
    };
    (void)hipLaunchCooperativeKernel((const void*)fused_kernel,
                                     dim3(NDB), dim3(TPB), args,
                                     NFL * sizeof(float), stream);
}

// Round 10
// 126.087 us; speedup vs baseline: 4.4078x; 4.4078x over previous
//
#include <hip/hip_runtime.h>

// Problem constants (from reference)
constexpr int   NB         = 128;          // bins per axis
constexpr int   NCELL      = NB * NB;      // 16384 cells
constexpr int   NFL        = 2 * NCELL;    // [Dx | Dy] floats = 32768
constexpr float S          = 7.8125f;      // 1000/128, exact in fp32
constexpr int   NUM_NETS   = 100000;
constexpr int   NUM_NODES  = 200000;
constexpr int   NUM_MOVABLE= 180000;
constexpr int   NUM_PINS   = 400000;
constexpr float UNIT_H_CAP = 1.5f;
constexpr float UNIT_V_CAP = 1.4f;

#define TPB    1024  // net_diff block size (16 waves)
#define NDB    256   // net_diff blocks: 1 per CU on ALL 256 CUs
#define NCHUNK 8     // reduce chunks == XCD count (XCD-affine slice sums)

// scanxy LDS geometry: padded pitch so the column-walk (y-scan) is
// conflict-free: bank = (2r + 2c) % 32 -> 2 lanes/bank (free, m136).
#define PADM2  129                  // float2 pitch
#define SEG    8                    // scan segments
#define SEGR   16                   // rows (cols) per segment

__device__ __forceinline__ float edgef(int t) { return (float)t * S; }

__device__ __forceinline__ int bin_of(float v) {
    int t = (int)floorf(v / S);
    while (edgef(t + 1) <= v) ++t;
    while (edgef(t)     >  v) --t;
    return t;
}

__device__ __forceinline__ float phi(int t, float lo, float hi) {
    return fminf(fmaxf(edgef(t), lo), hi);
}

// 4-lane-group bbox reduce (xor 1, xor 2 stay inside the group)
__device__ __forceinline__ void grp_reduce(float& xmin, float& xmax,
                                           float& ymin, float& ymax) {
    xmin = fminf(xmin, __shfl_xor(xmin, 1));
    xmin = fminf(xmin, __shfl_xor(xmin, 2));
    xmax = fmaxf(xmax, __shfl_xor(xmax, 1));
    xmax = fmaxf(xmax, __shfl_xor(xmax, 2));
    ymin = fminf(ymin, __shfl_xor(ymin, 1));
    ymin = fminf(ymin, __shfl_xor(ymin, 2));
    ymax = fmaxf(ymax, __shfl_xor(ymax, 1));
    ymax = fmaxf(ymax, __shfl_xor(ymax, 2));
}

// lane l's scatter of one net (lane owns x-entry l of the second difference)
__device__ __forceinline__ void scatter_net(
    float xmin, float xmax, float ymin, float ymax, float w,
    int l, float* __restrict__ Dl) {
    float dx = xmax - xmin, dy = ymax - ymin;
    float cx = (dy > 0.f) ? w / dy : 0.f;   // map_x coeff
    float cy = (dx > 0.f) ? w / dx : 0.f;   // map_y coeff
    if (cx == 0.f && cy == 0.f) return;

    int ax = bin_of(xmin), bx = bin_of(xmax);
    int row; bool has;
    if      (l == 0) { row = ax;     has = true; }
    else if (l == 1) { row = ax + 1; has = true; }
    else if (l == 2) { row = bx;     has = (bx > ax + 1); }
    else             { row = bx + 1; has = (bx > ax); }
    if (!has || row >= NB) return;
    float fi = phi(row + 1, xmin, xmax) - 2.f * phi(row, xmin, xmax)
             + phi(row - 1, xmin, xmax);
    if (fi == 0.f) return;

    int ay = bin_of(ymin), by = bin_of(ymax);
    #pragma unroll
    for (int j = 0; j < 4; ++j) {      // compile-time j: stays in regs
        int col; bool hj;
        if      (j == 0) { col = ay;     hj = true; }
        else if (j == 1) { col = ay + 1; hj = true; }
        else if (j == 2) { col = by;     hj = (by > ay + 1); }
        else             { col = by + 1; hj = (by > ay); }
        if (!hj || col >= NB) continue;
        float fj = phi(col + 1, ymin, ymax) - 2.f * phi(col, ymin, ymax)
                 + phi(col - 1, ymin, ymax);
        float t = fi * fj;
        if (t == 0.f) continue;
        int cell = row * NB + col;
        if (cx != 0.f) atomicAdd(&Dl[cell],         cx * t);
        if (cy != 0.f) atomicAdd(&Dl[NCELL + cell], cy * t);
    }
}

// K1: fused pin-parallel bbox gather + LDS scatter + bulk P writeback.
// NEW vs R6: 2-NET ILP BATCHING — each thread's two nets (n, n+GP) issue
// their full load chains (nps pair, fnp, pin_pos, weight) back-to-back
// before any compute, doubling the memory-level parallelism per wave.
// Rationale: the 256 MiB poison fill evicts L2/L3 every iteration, so the
// nps->fnp->pin_pos chain runs nearly cold (~900 cy/round); with only 16
// waves/CU the exposed latency is the fitted ~25 us gather cost.
__global__ __launch_bounds__(TPB) void net_diff_kernel(
    const float* __restrict__ pin_pos,
    const float* __restrict__ net_weights,
    const int*   __restrict__ nps,
    const int*   __restrict__ fnp,
    float* __restrict__ P) {            // [B][NFL]
    extern __shared__ float Dl[];       // [Dx NCELL | Dy NCELL]
    const int tid = threadIdx.x;

    float4* D4 = (float4*)Dl;
    for (int i = tid; i < NFL / 4; i += TPB) D4[i] = make_float4(0, 0, 0, 0);
    __syncthreads();

    const int per = (NUM_NETS + gridDim.x - 1) / gridDim.x;   // 391
    const int n0  = blockIdx.x * per;
    const int n1  = min(n0 + per, NUM_NETS);
    const int l   = tid & 3;       // lane within 4-lane group (pin index)
    const int g   = tid >> 2;      // group id within block
    constexpr int GP = TPB / 4;    // 256 nets per iteration

    for (int nA = n0 + g; nA < n1; nA += 2 * GP) {
        const int nB = nA + GP;
        const bool hasB = (nB < n1);

        // ---- load phase: both nets' chains issued together ----
        int sA = nps[nA], eA = nps[nA + 1];
        int sB = 0, eB = 0;
        if (hasB) { sB = nps[nB]; eB = nps[nB + 1]; }
        const bool okA = (eA > sA), okB = hasB && (eB > sB);
        const bool fA = okA && (eA - sA == 4);
        const bool fB = okB && (eB - sB == 4);
        int pinA = fA ? fnp[sA + l] : 0;
        int pinB = fB ? fnp[sB + l] : 0;
        float xvA = 0.f, yvA = 0.f, xvB = 0.f, yvB = 0.f;
        if (fA) { xvA = pin_pos[pinA]; yvA = pin_pos[pinA + NUM_PINS]; }
        if (fB) { xvB = pin_pos[pinB]; yvB = pin_pos[pinB + NUM_PINS]; }
        float wA = okA ? net_weights[nA] : 0.f;
        float wB = okB ? net_weights[nB] : 0.f;

        // ---- net A ----
        {
            float xmin, xmax, ymin, ymax;
            if (fA) { xmin = xvA; xmax = xvA; ymin = yvA; ymax = yvA; }
            else {
                xmin = 1e30f; xmax = -1e30f; ymin = 1e30f; ymax = -1e30f;
                if (okA && l == 0) {           // rare/never: serial fallback
                    for (int p = sA; p < eA; ++p) {
                        int pin = fnp[p];
                        float px = pin_pos[pin];
                        float py = pin_pos[pin + NUM_PINS];
                        xmin = fminf(xmin, px); xmax = fmaxf(xmax, px);
                        ymin = fminf(ymin, py); ymax = fmaxf(ymax, py);
                    }
                }
            }
            grp_reduce(xmin, xmax, ymin, ymax);
            if (okA) scatter_net(xmin, xmax, ymin, ymax, wA, l, Dl);
        }
        // ---- net B ----
        {
            float xmin, xmax, ymin, ymax;
            if (fB) { xmin = xvB; xmax = xvB; ymin = yvB; ymax = yvB; }
            else {
                xmin = 1e30f; xmax = -1e30f; ymin = 1e30f; ymax = -1e30f;
                if (okB && l == 0) {
                    for (int p = sB; p < eB; ++p) {
                        int pin = fnp[p];
                        float px = pin_pos[pin];
                        float py = pin_pos[pin + NUM_PINS];
                        xmin = fminf(xmin, px); xmax = fmaxf(xmax, px);
                        ymin = fminf(ymin, py); ymax = fmaxf(ymax, py);
                    }
                }
            }
            grp_reduce(xmin, xmax, ymin, ymax);
            if (okB) scatter_net(xmin, xmax, ymin, ymax, wB, l, Dl);
        }
    }
    __syncthreads();

    float4* Pb = (float4*)(P + (size_t)blockIdx.x * NFL);
    for (int i = tid; i < NFL / 4; i += TPB) Pb[i] = D4[i];
}

// K2: XCD-affine chunked reduce (unchanged from R6). Grid (8, 32):
// chunk = blockIdx.x -> linear block id % 8 == chunk ~= this block's XCD;
// sums slices b % 8 == chunk.
__global__ __launch_bounds__(256) void reduce_kernel(
    const float4* __restrict__ P,   // [B][NFL/4]
    float4* __restrict__ Rc,        // [NCHUNK][NFL/4]
    int B) {
    constexpr int NF4 = NFL / 4;    // 8192
    int g = blockIdx.y * blockDim.x + threadIdx.x;   // 0..8191
    int chunk = blockIdx.x;                          // 0..7
    float4 a0 = {0,0,0,0}, a1 = {0,0,0,0}, a2 = {0,0,0,0}, a3 = {0,0,0,0};
    int b = chunk;
    for (; b + 3 * NCHUNK < B; b += 4 * NCHUNK) {
        float4 v0 = P[(size_t)(b             ) * NF4 + g];
        float4 v1 = P[(size_t)(b +     NCHUNK) * NF4 + g];
        float4 v2 = P[(size_t)(b + 2 * NCHUNK) * NF4 + g];
        float4 v3 = P[(size_t)(b + 3 * NCHUNK) * NF4 + g];
        a0.x += v0.x; a0.y += v0.y; a0.z += v0.z; a0.w += v0.w;
        a1.x += v1.x; a1.y += v1.y; a1.z += v1.z; a1.w += v1.w;
        a2.x += v2.x; a2.y += v2.y; a2.z += v2.z; a2.w += v2.w;
        a3.x += v3.x; a3.y += v3.y; a3.z += v3.z; a3.w += v3.w;
    }
    for (; b < B; b += NCHUNK) {
        float4 v = P[(size_t)b * NF4 + g];
        a0.x += v.x; a0.y += v.y; a0.z += v.z; a0.w += v.w;
    }
    float4 r;
    r.x = (a0.x + a1.x) + (a2.x + a3.x);
    r.y = (a0.y + a1.y) + (a2.y + a3.y);
    r.z = (a0.z + a1.z) + (a2.z + a3.z);
    r.w = (a0.w + a1.w) + (a2.w + a3.w);
    Rc[(size_t)chunk * NF4 + g] = r;
}

// K3: fused x-scan + y-scan + clip in ONE 1024-thread block (saves one
// dispatch boundary + one kernel). 3-phase register-segment scans:
//   x-scan: thread (c = tid&127, s = tid>>7) serial-scans 16 rows in regs,
//   HS over the 8 segment totals, add exclusive offset. Then same along y.
// LDS: M[128][PADM2=129] float2 (133 KB) + T[8][128] float2 (8 KB) = 141 KB.
// Padding makes both row-walks and column-walks 2 lanes/bank (free).
__global__ __launch_bounds__(1024) void scanxy_kernel(
    const float* __restrict__ Rc,    // [NCHUNK][NFL]
    float* __restrict__ util) {      // [NCELL]
    extern __shared__ float2 M[];    // [NB * PADM2]
    float2* T = M + NB * PADM2;      // [SEG * NB]
    const int tid = threadIdx.x;

    // ---- x-scan (along r, fixed c) ----
    {
        const int c = tid & (NB - 1);
        const int s = tid >> 7;
        float2 run = make_float2(0.f, 0.f);
        for (int i = 0; i < SEGR; ++i) {
            int r = s * SEGR + i;
            int idx = r * NB + c;
            float vx = 0.f, vy = 0.f;
            #pragma unroll
            for (int ch = 0; ch < NCHUNK; ++ch) {
                vx += Rc[(size_t)ch * NFL + idx];
                vy += Rc[(size_t)ch * NFL + NCELL + idx];
            }
            run.x += vx; run.y += vy;
            M[r * PADM2 + c] = run;
        }
        T[s * NB + c] = run;
        __syncthreads();
        float2 v = T[s * NB + c];
        #pragma unroll
        for (int off = 1; off < SEG; off <<= 1) {
            float2 add = make_float2(0.f, 0.f);
            if (s >= off) add = T[(s - off) * NB + c];
            __syncthreads();
            v.x += add.x; v.y += add.y;
            T[s * NB + c] = v;
            __syncthreads();
        }
        float2 e = make_float2(0.f, 0.f);
        if (s > 0) e = T[(s - 1) * NB + c];
        for (int i = 0; i < SEGR; ++i) {
            int r = s * SEGR + i;
            float2 m = M[r * PADM2 + c];
            m.x += e.x; m.y += e.y;
            M[r * PADM2 + c] = m;
        }
    }
    __syncthreads();

    // ---- y-scan (along c, fixed r) + clip ----
    {
        const int r = tid & (NB - 1);
        const int s = tid >> 7;
        float2 run = make_float2(0.f, 0.f);
        for (int i = 0; i < SEGR; ++i) {
            int c = s * SEGR + i;
            float2 v = M[r * PADM2 + c];
            run.x += v.x; run.y += v.y;
            M[r * PADM2 + c] = run;
        }
        T[s * NB + r] = run;
        __syncthreads();
        float2 v = T[s * NB + r];
        #pragma unroll
        for (int off = 1; off < SEG; off <<= 1) {
            float2 add = make_float2(0.f, 0.f);
            if (s >= off) add = T[(s - off) * NB + r];
            __syncthreads();
            v.x += add.x; v.y += add.y;
            T[s * NB + r] = v;
            __syncthreads();
        }
        float2 e = make_float2(0.f, 0.f);
        if (s > 0) e = T[(s - 1) * NB + r];
        constexpr float invx = 1.f / (S * S * UNIT_H_CAP);
        constexpr float invy = 1.f / (S * S * UNIT_V_CAP);
        for (int i = 0; i < SEGR; ++i) {
            int c = s * SEGR + i;
            float2 m = M[r * PADM2 + c];
            float u = fmaxf((m.x + e.x) * invx, (m.y + e.y) * invy);
            M[r * PADM2 + c].x = fminf(fmaxf(u, 0.5f), 2.0f);
        }
    }
    __syncthreads();
    for (int cell = tid; cell < NCELL; cell += 1024)
        util[cell] = M[(cell >> 7) * PADM2 + (cell & (NB - 1))].x;
}

// K4: per-movable-node area = sum over <=3x3 bins of ox*util*oy
__global__ __launch_bounds__(256) void node_kernel(
    const float* __restrict__ pos,
    const float* __restrict__ nsx,
    const float* __restrict__ nsy,
    const float* __restrict__ util,
    float* __restrict__ out) {
    int m = blockIdx.x * blockDim.x + threadIdx.x;
    if (m >= NUM_MOVABLE) return;
    float x  = pos[m];
    float y  = pos[NUM_NODES + m];
    float xh = x + nsx[m];
    float yh = y + nsy[m];
    int ax = max(0,      (int)floorf(x  / S) - 1);
    int bx = min(NB - 1, (int)floorf(xh / S) + 1);
    int ay = max(0,      (int)floorf(y  / S) - 1);
    int by = min(NB - 1, (int)floorf(yh / S) + 1);
    float acc = 0.f;
    for (int i = ax; i <= bx; ++i) {
        float ov = fminf(edgef(i + 1), xh) - fmaxf(edgef(i), x);
        if (ov <= 0.f) continue;
        float inner = 0.f;
        for (int j = ay; j <= by; ++j) {
            float ovy = fminf(edgef(j + 1), yh) - fmaxf(edgef(j), y);
            if (ovy > 0.f) inner += ovy * util[i * NB + j];
        }
        acc += ov * inner;
    }
    out[m] = acc;
}

extern "C" void kernel_launch(void* const* d_in, const int* in_sizes, int n_in,
                              void* d_out, int out_size, void* d_ws, size_t ws_size,
                              hipStream_t stream) {
    const float* pos      = (const float*)d_in[0];
    const float* pin_pos  = (const float*)d_in[1];
    const float* nsx      = (const float*)d_in[2];
    const float* nsy      = (const float*)d_in[3];
    const float* nw       = (const float*)d_in[4];
    const int*   npstart  = (const int*)d_in[5];
    const int*   fnp      = (const int*)d_in[6];
    float*       out      = (float*)d_out;

    // ws layout (floats): Rc[NCHUNK*NFL] | util[NCELL] | P[B*NFL]
    float* w    = (float*)d_ws;
    float* Rc   = w;                           w += NCHUNK * NFL;
    float* util = w;                           w += NCELL;
    float* P    = w;

    size_t fixed = (size_t)(w - (float*)d_ws) * sizeof(float);
    int B = NDB;
    if (ws_size > fixed) {
        size_t fit = (ws_size - fixed) / ((size_t)NFL * sizeof(float));
        if ((size_t)B > fit) B = (int)fit;
    } else {
        B = 1;
    }
    if (B < 1) B = 1;

    const int scan_lds = (NB * PADM2 + SEG * NB) * (int)sizeof(float2);

    (void)hipFuncSetAttribute((const void*)net_diff_kernel,
                              hipFuncAttributeMaxDynamicSharedMemorySize,
                              NFL * (int)sizeof(float));
    (void)hipFuncSetAttribute((const void*)scanxy_kernel,
                              hipFuncAttributeMaxDynamicSharedMemorySize,
                              scan_lds);

    net_diff_kernel<<<B, TPB, NFL * sizeof(float), stream>>>(
        pin_pos, nw, npstart, fnp, P);
    {
        dim3 g(NCHUNK, NFL / 4 / 256);   // (8, 32): blockIdx.x == chunk == XCD
        reduce_kernel<<<g, 256, 0, stream>>>(
            (const float4*)P, (float4*)Rc, B);
    }
    scanxy_kernel<<<1, 1024, scan_lds, stream>>>(Rc, util);
    node_kernel<<<(NUM_MOVABLE + 255) / 256, 256, 0, stream>>>(
        pos, nsx, nsy, util, out);
}

// Round 11
// 113.879 us; speedup vs baseline: 4.8803x; 1.1072x over previous
//
#include <hip/hip_runtime.h>

// Problem constants (from reference)
constexpr int   NB         = 128;          // bins per axis
constexpr int   NCELL      = NB * NB;      // 16384 cells
constexpr int   NFL        = 2 * NCELL;    // [Dx | Dy] floats = 32768
constexpr float S          = 7.8125f;      // 1000/128, exact in fp32
constexpr int   NUM_NETS   = 100000;
constexpr int   NUM_NODES  = 200000;
constexpr int   NUM_MOVABLE= 180000;
constexpr int   NUM_PINS   = 400000;
constexpr float UNIT_H_CAP = 1.5f;
constexpr float UNIT_V_CAP = 1.4f;

#define TPB    1024  // net_diff block size (16 waves)
#define NDB    256   // net_diff blocks: 1 per CU on ALL 256 CUs
#define NCHUNK 8     // reduce chunks == XCD count (XCD-affine slice sums)

__device__ __forceinline__ float edgef(int t) { return (float)t * S; }

__device__ __forceinline__ int bin_of(float v) {
    int t = (int)floorf(v / S);
    while (edgef(t + 1) <= v) ++t;
    while (edgef(t)     >  v) --t;
    return t;
}

__device__ __forceinline__ float phi(int t, float lo, float hi) {
    return fminf(fmaxf(edgef(t), lo), hi);
}

// 4-lane-group bbox reduce (xor 1, xor 2 stay inside the group)
__device__ __forceinline__ void grp_reduce(float& xmin, float& xmax,
                                           float& ymin, float& ymax) {
    xmin = fminf(xmin, __shfl_xor(xmin, 1));
    xmin = fminf(xmin, __shfl_xor(xmin, 2));
    xmax = fmaxf(xmax, __shfl_xor(xmax, 1));
    xmax = fmaxf(xmax, __shfl_xor(xmax, 2));
    ymin = fminf(ymin, __shfl_xor(ymin, 1));
    ymin = fminf(ymin, __shfl_xor(ymin, 2));
    ymax = fmaxf(ymax, __shfl_xor(ymax, 1));
    ymax = fmaxf(ymax, __shfl_xor(ymax, 2));
}

// lane l's scatter of one net (lane owns x-entry l of the second difference)
__device__ __forceinline__ void scatter_net(
    float xmin, float xmax, float ymin, float ymax, float w,
    int l, float* __restrict__ Dl) {
    float dx = xmax - xmin, dy = ymax - ymin;
    float cx = (dy > 0.f) ? w / dy : 0.f;   // map_x coeff
    float cy = (dx > 0.f) ? w / dx : 0.f;   // map_y coeff
    if (cx == 0.f && cy == 0.f) return;

    int ax = bin_of(xmin), bx = bin_of(xmax);
    int row; bool has;
    if      (l == 0) { row = ax;     has = true; }
    else if (l == 1) { row = ax + 1; has = true; }
    else if (l == 2) { row = bx;     has = (bx > ax + 1); }
    else             { row = bx + 1; has = (bx > ax); }
    if (!has || row >= NB) return;
    float fi = phi(row + 1, xmin, xmax) - 2.f * phi(row, xmin, xmax)
             + phi(row - 1, xmin, xmax);
    if (fi == 0.f) return;

    int ay = bin_of(ymin), by = bin_of(ymax);
    #pragma unroll
    for (int j = 0; j < 4; ++j) {      // compile-time j: stays in regs
        int col; bool hj;
        if      (j == 0) { col = ay;     hj = true; }
        else if (j == 1) { col = ay + 1; hj = true; }
        else if (j == 2) { col = by;     hj = (by > ay + 1); }
        else             { col = by + 1; hj = (by > ay); }
        if (!hj || col >= NB) continue;
        float fj = phi(col + 1, ymin, ymax) - 2.f * phi(col, ymin, ymax)
                 + phi(col - 1, ymin, ymax);
        float t = fi * fj;
        if (t == 0.f) continue;
        int cell = row * NB + col;
        if (cx != 0.f) atomicAdd(&Dl[cell],         cx * t);
        if (cy != 0.f) atomicAdd(&Dl[NCELL + cell], cy * t);
    }
}

// K1: R6's fused pin-parallel bbox gather + LDS scatter + bulk P writeback,
// with ONE change (clean A/B vs R6): 2-NET ILP BATCHING. Each thread's two
// nets (n, n+GP) issue their full independent load chains (nps pair, fnp,
// pin_pos, weight) back-to-back before any compute -> 2x memory-level
// parallelism per thread. 391 nets / 256 groups means the batch covers the
// whole range in a single pass for most groups.
// Theory under test: net_diff's ~33us is MLP-limited cold-gather latency
// (the 256 MiB harness fill evicts L2/L3 each iteration).
__global__ __launch_bounds__(TPB) void net_diff_kernel(
    const float* __restrict__ pin_pos,
    const float* __restrict__ net_weights,
    const int*   __restrict__ nps,
    const int*   __restrict__ fnp,
    float* __restrict__ P) {            // [B][NFL]
    extern __shared__ float Dl[];       // [Dx NCELL | Dy NCELL]
    const int tid = threadIdx.x;

    float4* D4 = (float4*)Dl;
    for (int i = tid; i < NFL / 4; i += TPB) D4[i] = make_float4(0, 0, 0, 0);
    __syncthreads();

    const int per = (NUM_NETS + gridDim.x - 1) / gridDim.x;   // 391
    const int n0  = blockIdx.x * per;
    const int n1  = min(n0 + per, NUM_NETS);
    const int l   = tid & 3;       // lane within 4-lane group (pin index)
    const int g   = tid >> 2;      // group id within block
    constexpr int GP = TPB / 4;    // 256 nets per iteration

    for (int nA = n0 + g; nA < n1; nA += 2 * GP) {
        const int nB = nA + GP;
        const bool hasB = (nB < n1);

        // ---- load phase: both nets' chains issued together ----
        int sA = nps[nA], eA = nps[nA + 1];
        int sB = 0, eB = 0;
        if (hasB) { sB = nps[nB]; eB = nps[nB + 1]; }
        const bool okA = (eA > sA), okB = hasB && (eB > sB);
        const bool fA = okA && (eA - sA == 4);
        const bool fB = okB && (eB - sB == 4);
        int pinA = fA ? fnp[sA + l] : 0;
        int pinB = fB ? fnp[sB + l] : 0;
        float xvA = 0.f, yvA = 0.f, xvB = 0.f, yvB = 0.f;
        if (fA) { xvA = pin_pos[pinA]; yvA = pin_pos[pinA + NUM_PINS]; }
        if (fB) { xvB = pin_pos[pinB]; yvB = pin_pos[pinB + NUM_PINS]; }
        float wA = okA ? net_weights[nA] : 0.f;
        float wB = okB ? net_weights[nB] : 0.f;

        // ---- net A ----
        {
            float xmin, xmax, ymin, ymax;
            if (fA) { xmin = xvA; xmax = xvA; ymin = yvA; ymax = yvA; }
            else {
                xmin = 1e30f; xmax = -1e30f; ymin = 1e30f; ymax = -1e30f;
                if (okA && l == 0) {           // rare/never: serial fallback
                    for (int p = sA; p < eA; ++p) {
                        int pin = fnp[p];
                        float px = pin_pos[pin];
                        float py = pin_pos[pin + NUM_PINS];
                        xmin = fminf(xmin, px); xmax = fmaxf(xmax, px);
                        ymin = fminf(ymin, py); ymax = fmaxf(ymax, py);
                    }
                }
            }
            grp_reduce(xmin, xmax, ymin, ymax);
            if (okA) scatter_net(xmin, xmax, ymin, ymax, wA, l, Dl);
        }
        // ---- net B ----
        {
            float xmin, xmax, ymin, ymax;
            if (fB) { xmin = xvB; xmax = xvB; ymin = yvB; ymax = yvB; }
            else {
                xmin = 1e30f; xmax = -1e30f; ymin = 1e30f; ymax = -1e30f;
                if (okB && l == 0) {
                    for (int p = sB; p < eB; ++p) {
                        int pin = fnp[p];
                        float px = pin_pos[pin];
                        float py = pin_pos[pin + NUM_PINS];
                        xmin = fminf(xmin, px); xmax = fmaxf(xmax, px);
                        ymin = fminf(ymin, py); ymax = fmaxf(ymax, py);
                    }
                }
            }
            grp_reduce(xmin, xmax, ymin, ymax);
            if (okB) scatter_net(xmin, xmax, ymin, ymax, wB, l, Dl);
        }
    }
    __syncthreads();

    float4* Pb = (float4*)(P + (size_t)blockIdx.x * NFL);
    for (int i = tid; i < NFL / 4; i += TPB) Pb[i] = D4[i];
}

// K2: XCD-affine chunked reduce (R6, unchanged). Grid (8, 32):
// chunk = blockIdx.x -> linear block id % 8 == chunk ~= this block's XCD;
// sums slices b % 8 == chunk.
__global__ __launch_bounds__(256) void reduce_kernel(
    const float4* __restrict__ P,   // [B][NFL/4]
    float4* __restrict__ Rc,        // [NCHUNK][NFL/4]
    int B) {
    constexpr int NF4 = NFL / 4;    // 8192
    int g = blockIdx.y * blockDim.x + threadIdx.x;   // 0..8191
    int chunk = blockIdx.x;                          // 0..7
    float4 a0 = {0,0,0,0}, a1 = {0,0,0,0}, a2 = {0,0,0,0}, a3 = {0,0,0,0};
    int b = chunk;
    for (; b + 3 * NCHUNK < B; b += 4 * NCHUNK) {
        float4 v0 = P[(size_t)(b             ) * NF4 + g];
        float4 v1 = P[(size_t)(b +     NCHUNK) * NF4 + g];
        float4 v2 = P[(size_t)(b + 2 * NCHUNK) * NF4 + g];
        float4 v3 = P[(size_t)(b + 3 * NCHUNK) * NF4 + g];
        a0.x += v0.x; a0.y += v0.y; a0.z += v0.z; a0.w += v0.w;
        a1.x += v1.x; a1.y += v1.y; a1.z += v1.z; a1.w += v1.w;
        a2.x += v2.x; a2.y += v2.y; a2.z += v2.z; a2.w += v2.w;
        a3.x += v3.x; a3.y += v3.y; a3.z += v3.z; a3.w += v3.w;
    }
    for (; b < B; b += NCHUNK) {
        float4 v = P[(size_t)b * NF4 + g];
        a0.x += v.x; a0.y += v.y; a0.z += v.z; a0.w += v.w;
    }
    float4 r;
    r.x = (a0.x + a1.x) + (a2.x + a3.x);
    r.y = (a0.y + a1.y) + (a2.y + a3.y);
    r.z = (a0.z + a1.z) + (a2.z + a3.z);
    r.w = (a0.w + a1.w) + (a2.w + a3.w);
    Rc[(size_t)chunk * NF4 + g] = r;
}

// K3: x-prefix (R6, unchanged). One block per y-column; thread t = x-row.
__global__ __launch_bounds__(NB) void scan_x_kernel(
    const float* __restrict__ Rc,    // [NCHUNK][2][NCELL]
    float2* __restrict__ Xp) {       // [NCELL] float2, x-prefixed
    __shared__ float2 sm[NB];
    int col = blockIdx.x;
    int t = threadIdx.x;
    int idx = t * NB + col;
    float2 v = make_float2(0.f, 0.f);
    #pragma unroll
    for (int c = 0; c < NCHUNK; ++c) {
        v.x += Rc[(size_t)c * NFL + idx];
        v.y += Rc[(size_t)c * NFL + NCELL + idx];
    }
    sm[t] = v;
    __syncthreads();
    #pragma unroll
    for (int off = 1; off < NB; off <<= 1) {
        float2 cur = sm[t];
        float2 add = (t >= off) ? sm[t - off] : make_float2(0.f, 0.f);
        __syncthreads();
        cur.x += add.x; cur.y += add.y;
        sm[t] = cur;
        __syncthreads();
    }
    Xp[idx] = sm[t];
}

// K4: y-prefix + clip -> util (R6, unchanged). One block per x-row.
__global__ __launch_bounds__(NB) void scan_y_kernel(
    const float2* __restrict__ Xp,   // [NCELL] float2
    float* __restrict__ util) {
    __shared__ float2 sm[NB];
    int row = blockIdx.x;
    int t = threadIdx.x;
    sm[t] = Xp[row * NB + t];
    __syncthreads();
    #pragma unroll
    for (int off = 1; off < NB; off <<= 1) {
        float2 cur = sm[t];
        float2 add = (t >= off) ? sm[t - off] : make_float2(0.f, 0.f);
        __syncthreads();
        cur.x += add.x; cur.y += add.y;
        sm[t] = cur;
        __syncthreads();
    }
    constexpr float invx = 1.f / (S * S * UNIT_H_CAP);
    constexpr float invy = 1.f / (S * S * UNIT_V_CAP);
    float2 r = sm[t];
    float u = fmaxf(r.x * invx, r.y * invy);
    util[row * NB + t] = fminf(fmaxf(u, 0.5f), 2.0f);
}

// K5: per-movable-node area (R6, unchanged)
__global__ __launch_bounds__(256) void node_kernel(
    const float* __restrict__ pos,
    const float* __restrict__ nsx,
    const float* __restrict__ nsy,
    const float* __restrict__ util,
    float* __restrict__ out) {
    int m = blockIdx.x * blockDim.x + threadIdx.x;
    if (m >= NUM_MOVABLE) return;
    float x  = pos[m];
    float y  = pos[NUM_NODES + m];
    float xh = x + nsx[m];
    float yh = y + nsy[m];
    int ax = max(0,      (int)floorf(x  / S) - 1);
    int bx = min(NB - 1, (int)floorf(xh / S) + 1);
    int ay = max(0,      (int)floorf(y  / S) - 1);
    int by = min(NB - 1, (int)floorf(yh / S) + 1);
    float acc = 0.f;
    for (int i = ax; i <= bx; ++i) {
        float ov = fminf(edgef(i + 1), xh) - fmaxf(edgef(i), x);
        if (ov <= 0.f) continue;
        float inner = 0.f;
        for (int j = ay; j <= by; ++j) {
            float ovy = fminf(edgef(j + 1), yh) - fmaxf(edgef(j), y);
            if (ovy > 0.f) inner += ovy * util[i * NB + j];
        }
        acc += ov * inner;
    }
    out[m] = acc;
}

extern "C" void kernel_launch(void* const* d_in, const int* in_sizes, int n_in,
                              void* d_out, int out_size, void* d_ws, size_t ws_size,
                              hipStream_t stream) {
    const float* pos      = (const float*)d_in[0];
    const float* pin_pos  = (const float*)d_in[1];
    const float* nsx      = (const float*)d_in[2];
    const float* nsy      = (const float*)d_in[3];
    const float* nw       = (const float*)d_in[4];
    const int*   npstart  = (const int*)d_in[5];
    const int*   fnp      = (const int*)d_in[6];
    float*       out      = (float*)d_out;

    // ws layout (floats): Rc[NCHUNK*NFL] | Xp[NFL] | util[NCELL] | P[B*NFL]
    float* w    = (float*)d_ws;
    float* Rc   = w;                           w += NCHUNK * NFL;
    float* Xp   = w;                           w += NFL;
    float* util = w;                           w += NCELL;
    float* P    = w;

    size_t fixed = (size_t)(w - (float*)d_ws) * sizeof(float);
    int B = NDB;
    if (ws_size > fixed) {
        size_t fit = (ws_size - fixed) / ((size_t)NFL * sizeof(float));
        if ((size_t)B > fit) B = (int)fit;
    } else {
        B = 1;
    }
    if (B < 1) B = 1;

    (void)hipFuncSetAttribute((const void*)net_diff_kernel,
                              hipFuncAttributeMaxDynamicSharedMemorySize,
                              NFL * (int)sizeof(float));

    net_diff_kernel<<<B, TPB, NFL * sizeof(float), stream>>>(
        pin_pos, nw, npstart, fnp, P);
    {
        dim3 g(NCHUNK, NFL / 4 / 256);   // (8, 32): blockIdx.x == chunk == XCD
        reduce_kernel<<<g, 256, 0, stream>>>(
            (const float4*)P, (float4*)Rc, B);
    }
    scan_x_kernel<<<NB, NB, 0, stream>>>(Rc, (float2*)Xp);
    scan_y_kernel<<<NB, NB, 0, stream>>>((const float2*)Xp, util);
    node_kernel<<<(NUM_MOVABLE + 255) / 256, 256, 0, stream>>>(
        pos, nsx, nsy, util, out);
}